// Round 14
// baseline (179.624 us; speedup 1.0000x reference)
//
#include <hip/hip_runtime.h>
#include <cstdint>
#include <cstddef>

typedef _Float16 half_t;
typedef __attribute__((ext_vector_type(4))) _Float16 half4v;
typedef __attribute__((ext_vector_type(8))) _Float16 half8v;
typedef __attribute__((ext_vector_type(4))) float float4v;
typedef __attribute__((ext_vector_type(16))) float float16v;
typedef __attribute__((ext_vector_type(4))) unsigned uint4v;
typedef __attribute__((ext_vector_type(2))) int int2v;

typedef __attribute__((address_space(1))) const void gv_t;
typedef __attribute__((address_space(3))) void lv_t;

__device__ __forceinline__ void lds_cp16(const void* g, void* l) {
  __builtin_amdgcn_global_load_lds((gv_t*)g, (lv_t*)l, 16, 0, 0);
}

__device__ __forceinline__ unsigned pkh(float a, float b) {
  return __builtin_bit_cast(unsigned, __builtin_amdgcn_cvt_pkrtz(a, b));
}

// ---------------- convert fp32 -> fp16, vectorized x4 ----------------
__global__ __launch_bounds__(256) void k_cvt(const float* __restrict__ in,
                                             half_t* __restrict__ out) {
  int i = blockIdx.x * 256 + threadIdx.x;
  float4 v = ((const float4*)in)[i];
  half4v h = {(half_t)v.x, (half_t)v.y, (half_t)v.z, (half_t)v.w};
  ((half4v*)out)[i] = h;
}

// ---------- transpose + convert: in[R][C] fp32 -> out[C][R] fp16 ----------
__global__ __launch_bounds__(256) void k_tcvt(const float* __restrict__ in,
                                              half_t* __restrict__ out, int R, int C) {
  __shared__ float t[32][33];
  int c0 = blockIdx.x * 32, r0 = blockIdx.y * 32;
  int tc = threadIdx.x & 31, tr = threadIdx.x >> 5;  // tr 0..7
#pragma unroll
  for (int i = 0; i < 4; i++)
    t[tr + i * 8][tc] = in[(size_t)(r0 + tr + i * 8) * C + c0 + tc];
  __syncthreads();
#pragma unroll
  for (int i = 0; i < 4; i++)
    out[(size_t)(c0 + tr + i * 8) * R + r0 + tc] = (half_t)t[tc][tr + i * 8];
}

// ---------------- 128x128x64 fp16 MFMA GEMM, C = A @ Bt^T (round-10) --------
// BK=64, 2 LDS buffers, depth-1 prefetch post-barrier, vmcnt(0)+barrier/step,
// granule-XOR swizzle (pre-swizzled source, linear LDS dest), XCD/L2 chunks.
// EPI==0: QKV epilogue -> scatter Q/K/V^T + bias ; EPI==1: fp32 out + bias
template <int EPI>
__global__ __launch_bounds__(256, 2) void k_gemm(
    const half_t* __restrict__ A, const half_t* __restrict__ Bt,
    const float* __restrict__ bias, float* __restrict__ Cout,
    half_t* __restrict__ Qo, half_t* __restrict__ Ko, half_t* __restrict__ Vo,
    int M, int N, int K) {
  __shared__ half_t As[2][128 * 64];
  __shared__ half_t Bs[2][128 * 64];
  const int tid = threadIdx.x;
  const int lane = tid & 63;
  const int w = tid >> 6;
  const int xcd = blockIdx.x & 7;
  const int l = blockIdx.x >> 3;
  const int nc = l >> 6, r = l & 63;
  const int m0 = (xcd * 8 + (r >> 3)) * 128;
  const int n0 = (nc * 8 + (r & 7)) * 128;
  const int wr = w >> 1, wc = w & 1;

  int sr[4], sg[4];
#pragma unroll
  for (int j = 0; j < 4; ++j) {
    const int G = j * 256 + tid;
    sr[j] = G >> 3;
    sg[j] = (G & 7) ^ (sr[j] & 7);
  }

  float4v acc[4][4] = {};

  const int fr = lane & 15;
  const int fg = lane >> 4;
  const int so0 = fg ^ (fr & 7);
  const int so1 = (4 | fg) ^ (fr & 7);
  const int arow = wr * 64 + fr;
  const int brow = wc * 64 + fr;

  const int NT = K >> 6;
#pragma unroll
  for (int j = 0; j < 4; ++j) {
    lds_cp16(A + (size_t)(m0 + sr[j]) * K + sg[j] * 8, &As[0][(j * 256 + tid) * 8]);
    lds_cp16(Bt + (size_t)(n0 + sr[j]) * K + sg[j] * 8, &Bs[0][(j * 256 + tid) * 8]);
  }

  for (int t = 0; t < NT; t++) {
    asm volatile("s_waitcnt vmcnt(0)" ::: "memory");
    __builtin_amdgcn_s_barrier();
    __builtin_amdgcn_sched_barrier(0);
    const int cb = t & 1;
    if (t + 1 < NT) {
      const int kn = (t + 1) * 64;
#pragma unroll
      for (int j = 0; j < 4; ++j) {
        lds_cp16(A + (size_t)(m0 + sr[j]) * K + kn + sg[j] * 8,
                 &As[cb ^ 1][(j * 256 + tid) * 8]);
        lds_cp16(Bt + (size_t)(n0 + sr[j]) * K + kn + sg[j] * 8,
                 &Bs[cb ^ 1][(j * 256 + tid) * 8]);
      }
    }
    half8v a[4][2], b[4][2];
#pragma unroll
    for (int m = 0; m < 4; m++) {
      const int row = (arow + m * 16) * 64;
      a[m][0] = *(const half8v*)(&As[cb][row + so0 * 8]);
      a[m][1] = *(const half8v*)(&As[cb][row + so1 * 8]);
    }
#pragma unroll
    for (int n = 0; n < 4; n++) {
      const int row = (brow + n * 16) * 64;
      b[n][0] = *(const half8v*)(&Bs[cb][row + so0 * 8]);
      b[n][1] = *(const half8v*)(&Bs[cb][row + so1 * 8]);
    }
    __builtin_amdgcn_s_setprio(1);
#pragma unroll
    for (int kk = 0; kk < 2; kk++)
#pragma unroll
      for (int m = 0; m < 4; m++)
#pragma unroll
        for (int n = 0; n < 4; n++)
          acc[m][n] = __builtin_amdgcn_mfma_f32_16x16x32_f16(a[m][kk], b[n][kk],
                                                             acc[m][n], 0, 0, 0);
    __builtin_amdgcn_s_setprio(0);
  }

  const int rq = (lane >> 4) * 4;
  const int cc = lane & 15;
  if constexpr (EPI == 0) {
#pragma unroll
    for (int n = 0; n < 4; n++) {
      int e = n0 + wc * 64 + n * 16 + cc;
      float bv = bias[e];
      int which = e >> 10, h = (e >> 6) & 15, hd = e & 63;
#pragma unroll
      for (int m = 0; m < 4; m++) {
        int rowb = m0 + wr * 64 + m * 16 + rq;
#pragma unroll
        for (int r2 = 0; r2 < 4; r2++) {
          int row = rowb + r2;
          int b_ = row >> 10, tok = row & 1023;
          half_t hv = (half_t)(acc[m][n][r2] + bv);
          size_t bh = (size_t)(b_ * 16 + h);
          if (which == 0)
            Qo[(bh * 1024 + tok) * 64 + hd] = hv;
          else if (which == 1)
            Ko[(bh * 1024 + tok) * 64 + hd] = hv;
          else
            Vo[(bh * 64 + hd) * 1024 + tok] = hv;
        }
      }
    }
  } else {
#pragma unroll
    for (int n = 0; n < 4; n++) {
      int e = n0 + wc * 64 + n * 16 + cc;
      float bv = bias[e];
#pragma unroll
      for (int m = 0; m < 4; m++) {
        int rowb = m0 + wr * 64 + m * 16 + rq;
#pragma unroll
        for (int r2 = 0; r2 < 4; r2++)
          Cout[(size_t)(rowb + r2) * N + e] = acc[m][n][r2] + bv;
      }
    }
  }
}

// ---------------- flash attention: swapped-operand 32x32, in-register P ----
// exp2-domain softmax: Q pre-scaled by 0.125*log2(e), so sacc is in log2
// units; exp2f maps to bare v_exp_f32 (no per-element mul). Defer-max
// threshold 8*log2(e) = 11.5417 keeps the same e^8 P-bound.
__global__ __launch_bounds__(512, 4) void k_attn(const half_t* __restrict__ Qh,
                                                 const half_t* __restrict__ Kh,
                                                 const half_t* __restrict__ Vt,
                                                 half_t* __restrict__ ctx) {
  __shared__ alignas(16) half_t Ks[2][64 * 64];
  __shared__ alignas(16) half_t Vs[2][64 * 64];
  const int lane = threadIdx.x & 63;
  const int w = threadIdx.x >> 6;
  const int ql = lane & 31, hi = lane >> 5;
  const int xcd = blockIdx.x & 7, loc = blockIdx.x >> 3;
  const int bh = xcd * 16 + (loc >> 2), qb = loc & 3;
  const int b_ = bh >> 4, h = bh & 15;
  const int q0 = qb * 256 + w * 32;

  const half_t* Qp = Qh + (size_t)bh * (1024 * 64);
  const half_t* Kp = Kh + (size_t)bh * (1024 * 64);
  const half_t* Vp = Vt + (size_t)bh * (64 * 1024);

  half8v qf[4];
#pragma unroll
  for (int c = 0; c < 4; c++) {
    half8v tq = *(const half8v*)(Qp + (size_t)(q0 + ql) * 64 + c * 16 + hi * 8);
    qf[c] = tq * (_Float16)0.18033688f;  // 0.125 * log2(e)
  }

  const int G = w * 64 + lane;
  const int rS = G >> 3;
  const int gS = (G & 7) ^ (rS & 7);

  float16v co[2] = {};
  float mr = -1e30f, ssum = 0.f;

  lds_cp16(Kp + (size_t)rS * 64 + gS * 8, &Ks[0][w * 512]);
  lds_cp16(Vp + (size_t)rS * 1024 + 0 + gS * 8, &Vs[0][w * 512]);
  __syncthreads();

  int cur = 0;
  for (int t = 0; t < 16; t++) {
    if (t < 15) {
      const int kn = (t + 1) * 64;
      lds_cp16(Kp + (size_t)(kn + rS) * 64 + gS * 8, &Ks[cur ^ 1][w * 512]);
      lds_cp16(Vp + (size_t)rS * 1024 + kn + gS * 8, &Vs[cur ^ 1][w * 512]);
    }

    float16v sacc[2] = {};
    __builtin_amdgcn_s_setprio(1);
#pragma unroll
    for (int c = 0; c < 4; c++)
#pragma unroll
      for (int s = 0; s < 2; s++) {
        int row = s * 32 + ql;
        half8v kf = *(const half8v*)(&Ks[cur][row * 64 + (((2 * c + hi) ^ (row & 7)) * 8)]);
        sacc[s] = __builtin_amdgcn_mfma_f32_32x32x16_f16(kf, qf[c], sacc[s], 0, 0, 0);
      }
    __builtin_amdgcn_s_setprio(0);

    // pairwise max tree (v_max3-fusable)
    float mx = fmaxf(fmaxf(sacc[0][0], sacc[0][1]), fmaxf(sacc[0][2], sacc[0][3]));
#pragma unroll
    for (int s = 0; s < 2; s++)
#pragma unroll
      for (int i = (s == 0 ? 4 : 0); i < 16; i += 4)
        mx = fmaxf(mx, fmaxf(fmaxf(sacc[s][i], sacc[s][i + 1]),
                             fmaxf(sacc[s][i + 2], sacc[s][i + 3])));
    mx = fmaxf(mx, __shfl_xor(mx, 32, 64));
    if (mx > mr + 11.5417f) {  // 8 * log2(e)
      float fac = exp2f(mr - mx);
      mr = mx;
      ssum *= fac;
#pragma unroll
      for (int dd = 0; dd < 2; dd++)
#pragma unroll
        for (int i = 0; i < 16; i++) co[dd][i] *= fac;
    }
    float rsum = 0.f;
#pragma unroll
    for (int s = 0; s < 2; s++)
#pragma unroll
      for (int i = 0; i < 16; i++) {
        float e = exp2f(sacc[s][i] - mr);
        sacc[s][i] = e;
        rsum += e;
      }
    rsum += __shfl_xor(rsum, 32, 64);
    ssum += rsum;

#pragma unroll
    for (int kc = 0; kc < 4; kc++) {
      const int s = kc >> 1, o = (kc & 1) * 8;
      unsigned dA0 = pkh(sacc[s][o + 0], sacc[s][o + 1]);
      unsigned dA1 = pkh(sacc[s][o + 2], sacc[s][o + 3]);
      unsigned dB0 = pkh(sacc[s][o + 4], sacc[s][o + 5]);
      unsigned dB1 = pkh(sacc[s][o + 6], sacc[s][o + 7]);
      int2v r0 = __builtin_amdgcn_permlane32_swap((int)dA0, (int)dB0, false, false);
      int2v r1 = __builtin_amdgcn_permlane32_swap((int)dA1, (int)dB1, false, false);
      uint4v pw = {(unsigned)r0.x, (unsigned)r1.x, (unsigned)r0.y, (unsigned)r1.y};
      half8v pf = __builtin_bit_cast(half8v, pw);
      __builtin_amdgcn_s_setprio(1);
#pragma unroll
      for (int dd = 0; dd < 2; dd++) {
        int row = dd * 32 + ql;
        half8v vf = *(const half8v*)(&Vs[cur][row * 64 + (((2 * kc + hi) ^ (row & 7)) * 8)]);
        co[dd] = __builtin_amdgcn_mfma_f32_32x32x16_f16(vf, pf, co[dd], 0, 0, 0);
      }
      __builtin_amdgcn_s_setprio(0);
    }
    __syncthreads();
    cur ^= 1;
  }

  float rinv = 1.0f / ssum;
  half_t* outp = ctx + ((size_t)(b_ * 1024 + q0 + ql) * 1024 + h * 64);
#pragma unroll
  for (int dd = 0; dd < 2; dd++)
#pragma unroll
    for (int g = 0; g < 4; g++) {
      int d0 = dd * 32 + g * 8 + hi * 4;
      unsigned p0 = pkh(co[dd][g * 4 + 0] * rinv, co[dd][g * 4 + 1] * rinv);
      unsigned p1 = pkh(co[dd][g * 4 + 2] * rinv, co[dd][g * 4 + 3] * rinv);
      *(unsigned*)(outp + d0) = p0;
      *(unsigned*)(outp + d0 + 2) = p1;
    }
}

extern "C" void kernel_launch(void* const* d_in, const int* in_sizes, int n_in,
                              void* d_out, int out_size, void* d_ws, size_t ws_size,
                              hipStream_t stream) {
  const float* x = (const float*)d_in[0];
  const float* Wqkv = (const float*)d_in[1];
  const float* bqkv = (const float*)d_in[2];
  const float* Wo = (const float*)d_in[3];
  const float* bo = (const float*)d_in[4];
  float* out = (float*)d_out;
  char* ws = (char*)d_ws;

  const size_t NEED = 75497472;
  if (ws_size < NEED) return;
  half_t* xh = (half_t*)(ws);
  half_t* wqkvT = (half_t*)(ws + 16777216);
  half_t* woT = (half_t*)(ws + 23068672);
  half_t* Qh = (half_t*)(ws + 25165824);
  half_t* Kh = (half_t*)(ws + 41943040);
  half_t* Vt = (half_t*)(ws + 58720256);
  half_t* ctxh = xh;

  k_cvt<<<8192, 256, 0, stream>>>(x, xh);
  k_tcvt<<<dim3(96, 32), 256, 0, stream>>>(Wqkv, wqkvT, 1024, 3072);
  k_tcvt<<<dim3(32, 32), 256, 0, stream>>>(Wo, woT, 1024, 1024);
  k_gemm<0><<<1536, 256, 0, stream>>>(xh, wqkvT, bqkv, nullptr, Qh, Kh, Vt,
                                      8192, 3072, 1024);
  k_attn<<<512, 512, 0, stream>>>(Qh, Kh, Vt, ctxh);
  k_gemm<1><<<512, 256, 0, stream>>>(ctxh, woT, bo, out, nullptr, nullptr, nullptr,
                                     8192, 1024, 1024);
}

// Round 15
// 170.589 us; speedup vs baseline: 1.0530x; 1.0530x over previous
//
#include <hip/hip_runtime.h>
#include <cstdint>
#include <cstddef>

typedef _Float16 half_t;
typedef __attribute__((ext_vector_type(4))) _Float16 half4v;
typedef __attribute__((ext_vector_type(8))) _Float16 half8v;
typedef __attribute__((ext_vector_type(4))) float float4v;
typedef __attribute__((ext_vector_type(16))) float float16v;
typedef __attribute__((ext_vector_type(4))) unsigned uint4v;
typedef __attribute__((ext_vector_type(2))) int int2v;

typedef __attribute__((address_space(1))) const void gv_t;
typedef __attribute__((address_space(3))) void lv_t;

__device__ __forceinline__ void lds_cp16(const void* g, void* l) {
  __builtin_amdgcn_global_load_lds((gv_t*)g, (lv_t*)l, 16, 0, 0);
}

__device__ __forceinline__ unsigned pkh(float a, float b) {
  return __builtin_bit_cast(unsigned, __builtin_amdgcn_cvt_pkrtz(a, b));
}

// ---------------- convert fp32 -> fp16, vectorized x4 ----------------
__global__ __launch_bounds__(256) void k_cvt(const float* __restrict__ in,
                                             half_t* __restrict__ out) {
  int i = blockIdx.x * 256 + threadIdx.x;
  float4 v = ((const float4*)in)[i];
  half4v h = {(half_t)v.x, (half_t)v.y, (half_t)v.z, (half_t)v.w};
  ((half4v*)out)[i] = h;
}

// ---------- transpose + convert: in[R][C] fp32 -> out[C][R] fp16 ----------
__global__ __launch_bounds__(256) void k_tcvt(const float* __restrict__ in,
                                              half_t* __restrict__ out, int R, int C) {
  __shared__ float t[32][33];
  int c0 = blockIdx.x * 32, r0 = blockIdx.y * 32;
  int tc = threadIdx.x & 31, tr = threadIdx.x >> 5;  // tr 0..7
#pragma unroll
  for (int i = 0; i < 4; i++)
    t[tr + i * 8][tc] = in[(size_t)(r0 + tr + i * 8) * C + c0 + tc];
  __syncthreads();
#pragma unroll
  for (int i = 0; i < 4; i++)
    out[(size_t)(c0 + tr + i * 8) * R + r0 + tc] = (half_t)t[tc][tr + i * 8];
}

// ---------------- 128x128x64 fp16 MFMA GEMM, C = A @ Bt^T ----------------
// BK=64, 2 LDS buffers, depth-1 prefetch post-barrier, vmcnt(0)+barrier/step,
// granule-XOR swizzle (pre-swizzled source, linear LDS dest), XCD/L2 chunks.
// EPI==0: QKV epilogue -> scatter Q/K/V^T + bias ; EPI==1: fp32 out + bias
template <int EPI>
__global__ __launch_bounds__(256, 2) void k_gemm(
    const half_t* __restrict__ A, const half_t* __restrict__ Bt,
    const float* __restrict__ bias, float* __restrict__ Cout,
    half_t* __restrict__ Qo, half_t* __restrict__ Ko, half_t* __restrict__ Vo,
    int M, int N, int K) {
  __shared__ half_t As[2][128 * 64];
  __shared__ half_t Bs[2][128 * 64];
  const int tid = threadIdx.x;
  const int lane = tid & 63;
  const int w = tid >> 6;
  const int xcd = blockIdx.x & 7;
  const int l = blockIdx.x >> 3;
  const int nc = l >> 6, r = l & 63;
  const int m0 = (xcd * 8 + (r >> 3)) * 128;
  const int n0 = (nc * 8 + (r & 7)) * 128;
  const int wr = w >> 1, wc = w & 1;

  int sr[4], sg[4];
#pragma unroll
  for (int j = 0; j < 4; ++j) {
    const int G = j * 256 + tid;
    sr[j] = G >> 3;
    sg[j] = (G & 7) ^ (sr[j] & 7);
  }

  float4v acc[4][4] = {};

  const int fr = lane & 15;
  const int fg = lane >> 4;
  const int so0 = fg ^ (fr & 7);
  const int so1 = (4 | fg) ^ (fr & 7);
  const int arow = wr * 64 + fr;
  const int brow = wc * 64 + fr;

  const int NT = K >> 6;
#pragma unroll
  for (int j = 0; j < 4; ++j) {
    lds_cp16(A + (size_t)(m0 + sr[j]) * K + sg[j] * 8, &As[0][(j * 256 + tid) * 8]);
    lds_cp16(Bt + (size_t)(n0 + sr[j]) * K + sg[j] * 8, &Bs[0][(j * 256 + tid) * 8]);
  }

  for (int t = 0; t < NT; t++) {
    asm volatile("s_waitcnt vmcnt(0)" ::: "memory");
    __builtin_amdgcn_s_barrier();
    __builtin_amdgcn_sched_barrier(0);
    const int cb = t & 1;
    if (t + 1 < NT) {
      const int kn = (t + 1) * 64;
#pragma unroll
      for (int j = 0; j < 4; ++j) {
        lds_cp16(A + (size_t)(m0 + sr[j]) * K + kn + sg[j] * 8,
                 &As[cb ^ 1][(j * 256 + tid) * 8]);
        lds_cp16(Bt + (size_t)(n0 + sr[j]) * K + kn + sg[j] * 8,
                 &Bs[cb ^ 1][(j * 256 + tid) * 8]);
      }
    }
    half8v a[4][2], b[4][2];
#pragma unroll
    for (int m = 0; m < 4; m++) {
      const int row = (arow + m * 16) * 64;
      a[m][0] = *(const half8v*)(&As[cb][row + so0 * 8]);
      a[m][1] = *(const half8v*)(&As[cb][row + so1 * 8]);
    }
#pragma unroll
    for (int n = 0; n < 4; n++) {
      const int row = (brow + n * 16) * 64;
      b[n][0] = *(const half8v*)(&Bs[cb][row + so0 * 8]);
      b[n][1] = *(const half8v*)(&Bs[cb][row + so1 * 8]);
    }
    __builtin_amdgcn_s_setprio(1);
#pragma unroll
    for (int kk = 0; kk < 2; kk++)
#pragma unroll
      for (int m = 0; m < 4; m++)
#pragma unroll
        for (int n = 0; n < 4; n++)
          acc[m][n] = __builtin_amdgcn_mfma_f32_16x16x32_f16(a[m][kk], b[n][kk],
                                                             acc[m][n], 0, 0, 0);
    __builtin_amdgcn_s_setprio(0);
  }

  const int rq = (lane >> 4) * 4;
  const int cc = lane & 15;
  if constexpr (EPI == 0) {
#pragma unroll
    for (int n = 0; n < 4; n++) {
      int e = n0 + wc * 64 + n * 16 + cc;
      float bv = bias[e];
      int which = e >> 10, h = (e >> 6) & 15, hd = e & 63;
#pragma unroll
      for (int m = 0; m < 4; m++) {
        int rowb = m0 + wr * 64 + m * 16 + rq;
#pragma unroll
        for (int r2 = 0; r2 < 4; r2++) {
          int row = rowb + r2;
          int b_ = row >> 10, tok = row & 1023;
          half_t hv = (half_t)(acc[m][n][r2] + bv);
          size_t bh = (size_t)(b_ * 16 + h);
          if (which == 0)
            Qo[(bh * 1024 + tok) * 64 + hd] = hv;
          else if (which == 1)
            Ko[(bh * 1024 + tok) * 64 + hd] = hv;
          else
            Vo[(bh * 64 + hd) * 1024 + tok] = hv;
        }
      }
    }
  } else {
#pragma unroll
    for (int n = 0; n < 4; n++) {
      int e = n0 + wc * 64 + n * 16 + cc;
      float bv = bias[e];
#pragma unroll
      for (int m = 0; m < 4; m++) {
        int rowb = m0 + wr * 64 + m * 16 + rq;
#pragma unroll
        for (int r2 = 0; r2 < 4; r2++)
          Cout[(size_t)(rowb + r2) * N + e] = acc[m][n][r2] + bv;
      }
    }
  }
}

// ---------------- flash attention: swapped-operand 32x32, in-register P ----
__global__ __launch_bounds__(512, 4) void k_attn(const half_t* __restrict__ Qh,
                                                 const half_t* __restrict__ Kh,
                                                 const half_t* __restrict__ Vt,
                                                 half_t* __restrict__ ctx) {
  __shared__ alignas(16) half_t Ks[2][64 * 64];
  __shared__ alignas(16) half_t Vs[2][64 * 64];
  const int lane = threadIdx.x & 63;
  const int w = threadIdx.x >> 6;
  const int ql = lane & 31, hi = lane >> 5;
  const int xcd = blockIdx.x & 7, loc = blockIdx.x >> 3;
  const int bh = xcd * 16 + (loc >> 2), qb = loc & 3;
  const int b_ = bh >> 4, h = bh & 15;
  const int q0 = qb * 256 + w * 32;

  const half_t* Qp = Qh + (size_t)bh * (1024 * 64);
  const half_t* Kp = Kh + (size_t)bh * (1024 * 64);
  const half_t* Vp = Vt + (size_t)bh * (64 * 1024);

  half8v qf[4];
#pragma unroll
  for (int c = 0; c < 4; c++) {
    half8v tq = *(const half8v*)(Qp + (size_t)(q0 + ql) * 64 + c * 16 + hi * 8);
    qf[c] = tq * (_Float16)0.125f;
  }

  const int G = w * 64 + lane;
  const int rS = G >> 3;
  const int gS = (G & 7) ^ (rS & 7);

  float16v co[2] = {};
  float mr = -1e30f, ssum = 0.f;

  lds_cp16(Kp + (size_t)rS * 64 + gS * 8, &Ks[0][w * 512]);
  lds_cp16(Vp + (size_t)rS * 1024 + 0 + gS * 8, &Vs[0][w * 512]);
  __syncthreads();

  int cur = 0;
  for (int t = 0; t < 16; t++) {
    if (t < 15) {
      const int kn = (t + 1) * 64;
      lds_cp16(Kp + (size_t)(kn + rS) * 64 + gS * 8, &Ks[cur ^ 1][w * 512]);
      lds_cp16(Vp + (size_t)rS * 1024 + kn + gS * 8, &Vs[cur ^ 1][w * 512]);
    }

    float16v sacc[2] = {};
    __builtin_amdgcn_s_setprio(1);
#pragma unroll
    for (int c = 0; c < 4; c++)
#pragma unroll
      for (int s = 0; s < 2; s++) {
        int row = s * 32 + ql;
        half8v kf = *(const half8v*)(&Ks[cur][row * 64 + (((2 * c + hi) ^ (row & 7)) * 8)]);
        sacc[s] = __builtin_amdgcn_mfma_f32_32x32x16_f16(kf, qf[c], sacc[s], 0, 0, 0);
      }
    __builtin_amdgcn_s_setprio(0);

    float mx = -1e30f;
#pragma unroll
    for (int s = 0; s < 2; s++)
#pragma unroll
      for (int i = 0; i < 16; i++) mx = fmaxf(mx, sacc[s][i]);
    mx = fmaxf(mx, __shfl_xor(mx, 32, 64));
    if (mx > mr + 8.f) {
      float fac = __expf(mr - mx);
      mr = mx;
      ssum *= fac;
#pragma unroll
      for (int dd = 0; dd < 2; dd++)
#pragma unroll
        for (int i = 0; i < 16; i++) co[dd][i] *= fac;
    }
    float rsum = 0.f;
#pragma unroll
    for (int s = 0; s < 2; s++)
#pragma unroll
      for (int i = 0; i < 16; i++) {
        float e = __expf(sacc[s][i] - mr);
        sacc[s][i] = e;
        rsum += e;
      }
    rsum += __shfl_xor(rsum, 32, 64);
    ssum += rsum;

#pragma unroll
    for (int kc = 0; kc < 4; kc++) {
      const int s = kc >> 1, o = (kc & 1) * 8;
      unsigned dA0 = pkh(sacc[s][o + 0], sacc[s][o + 1]);
      unsigned dA1 = pkh(sacc[s][o + 2], sacc[s][o + 3]);
      unsigned dB0 = pkh(sacc[s][o + 4], sacc[s][o + 5]);
      unsigned dB1 = pkh(sacc[s][o + 6], sacc[s][o + 7]);
      int2v r0 = __builtin_amdgcn_permlane32_swap((int)dA0, (int)dB0, false, false);
      int2v r1 = __builtin_amdgcn_permlane32_swap((int)dA1, (int)dB1, false, false);
      uint4v pw = {(unsigned)r0.x, (unsigned)r1.x, (unsigned)r0.y, (unsigned)r1.y};
      half8v pf = __builtin_bit_cast(half8v, pw);
      __builtin_amdgcn_s_setprio(1);
#pragma unroll
      for (int dd = 0; dd < 2; dd++) {
        int row = dd * 32 + ql;
        half8v vf = *(const half8v*)(&Vs[cur][row * 64 + (((2 * kc + hi) ^ (row & 7)) * 8)]);
        co[dd] = __builtin_amdgcn_mfma_f32_32x32x16_f16(vf, pf, co[dd], 0, 0, 0);
      }
      __builtin_amdgcn_s_setprio(0);
    }
    __syncthreads();
    cur ^= 1;
  }

  float rinv = 1.0f / ssum;
  half_t* outp = ctx + ((size_t)(b_ * 1024 + q0 + ql) * 1024 + h * 64);
#pragma unroll
  for (int dd = 0; dd < 2; dd++)
#pragma unroll
    for (int g = 0; g < 4; g++) {
      int d0 = dd * 32 + g * 8 + hi * 4;
      unsigned p0 = pkh(co[dd][g * 4 + 0] * rinv, co[dd][g * 4 + 1] * rinv);
      unsigned p1 = pkh(co[dd][g * 4 + 2] * rinv, co[dd][g * 4 + 3] * rinv);
      *(unsigned*)(outp + d0) = p0;
      *(unsigned*)(outp + d0 + 2) = p1;
    }
}

extern "C" void kernel_launch(void* const* d_in, const int* in_sizes, int n_in,
                              void* d_out, int out_size, void* d_ws, size_t ws_size,
                              hipStream_t stream) {
  const float* x = (const float*)d_in[0];
  const float* Wqkv = (const float*)d_in[1];
  const float* bqkv = (const float*)d_in[2];
  const float* Wo = (const float*)d_in[3];
  const float* bo = (const float*)d_in[4];
  float* out = (float*)d_out;
  char* ws = (char*)d_ws;

  const size_t NEED = 75497472;
  if (ws_size < NEED) return;
  half_t* xh = (half_t*)(ws);
  half_t* wqkvT = (half_t*)(ws + 16777216);
  half_t* woT = (half_t*)(ws + 23068672);
  half_t* Qh = (half_t*)(ws + 25165824);
  half_t* Kh = (half_t*)(ws + 41943040);
  half_t* Vt = (half_t*)(ws + 58720256);
  half_t* ctxh = xh;

  k_cvt<<<8192, 256, 0, stream>>>(x, xh);
  k_tcvt<<<dim3(96, 32), 256, 0, stream>>>(Wqkv, wqkvT, 1024, 3072);
  k_tcvt<<<dim3(32, 32), 256, 0, stream>>>(Wo, woT, 1024, 1024);
  k_gemm<0><<<1536, 256, 0, stream>>>(xh, wqkvT, bqkv, nullptr, Qh, Kh, Vt,
                                      8192, 3072, 1024);
  k_attn<<<512, 512, 0, stream>>>(Qh, Kh, Vt, ctxh);
  k_gemm<1><<<512, 256, 0, stream>>>(ctxh, woT, bo, out, nullptr, nullptr, nullptr,
                                     8192, 1024, 1024);
}